// Round 1
// baseline (2188.629 us; speedup 1.0000x reference)
//
#include <hip/hip_runtime.h>

// Problem constants
#define D1 8
#define D2 16
#define HH 64
#define WW 64
#define SPATIAL (D1*D2*HH*WW)   // 524288
#define COUT 32
#define EPS 1e-5f
#define NEG_SLOPE 0.2f

// ---------------------------------------------------------------------------
// Direct 4D conv (3x3x3x3, pad 1, stride 1), fp32.
// Block: 256 threads. Each block: fixed (a,b), 8 H-rows x 64 W, all 32 Cout.
// Thread: 4 cout x 16 w-positions = 64 accumulators.
// ---------------------------------------------------------------------------
template<int CIN>
__global__ __launch_bounds__(256)
void conv4d_kernel(const float* __restrict__ x, const float* __restrict__ wgt,
                   float* __restrict__ y)
{
    __shared__ float xs[10 * 66];   // rows h0-1..h0+8, cols -1..64
    __shared__ float wsl[288];      // [co 0..31][dh*3+dw 0..8]

    const int tid   = threadIdx.x;
    const int htile = blockIdx.x;   // 0..7
    const int b     = blockIdx.y;   // 0..15
    const int a     = blockIdx.z;   // 0..7
    const int h0    = htile * 8;

    const int cog   = tid >> 5;        // 0..7  -> cout group of 4
    const int wit   = tid & 31;
    const int r     = wit >> 2;        // 0..7  -> row within tile
    const int wbase = (wit & 3) << 4;  // 0,16,32,48

    float acc[4][16];
    #pragma unroll
    for (int j = 0; j < 4; ++j)
        #pragma unroll
        for (int i = 0; i < 16; ++i) acc[j][i] = 0.f;

    for (int ci = 0; ci < CIN; ++ci) {
        for (int da = 0; da < 3; ++da) {
            const int ap = a + da - 1;
            if (ap < 0 || ap >= D1) continue;          // block-uniform
            for (int db = 0; db < 3; ++db) {
                const int bp = b + db - 1;
                if (bp < 0 || bp >= D2) continue;      // block-uniform

                __syncthreads();   // protect previous slice's LDS

                // stage input plane rows h0-1..h0+8, cols -1..64
                const float* xplane =
                    x + (((long long)ci * D1 + ap) * D2 + bp) * (HH * WW);
                for (int e = tid; e < 660; e += 256) {
                    const int row = e / 66;
                    const int col = e - row * 66;
                    const int hh = h0 - 1 + row;
                    const int wc = col - 1;
                    float v = 0.f;
                    if (hh >= 0 && hh < HH && wc >= 0 && wc < WW)
                        v = xplane[hh * WW + wc];
                    xs[e] = v;
                }
                // stage weight slice (all 32 cout, 9 taps of this (ci,da,db))
                const int sl = (da * 3 + db) * 9;
                for (int e = tid; e < 288; e += 256) {
                    const int co  = e / 9;
                    const int tap = e - co * 9;
                    wsl[e] = wgt[(co * CIN + ci) * 81 + sl + tap];
                }
                __syncthreads();

                // weights -> registers (broadcast reads, 2 addrs per wave)
                float wr[4][9];
                #pragma unroll
                for (int j = 0; j < 4; ++j)
                    #pragma unroll
                    for (int t = 0; t < 9; ++t)
                        wr[j][t] = wsl[(cog * 4 + j) * 9 + t];

                #pragma unroll
                for (int dh = 0; dh < 3; ++dh) {
                    float xv[18];
                    const int rowbase = (r + dh) * 66 + wbase;
                    #pragma unroll
                    for (int k = 0; k < 18; ++k) xv[k] = xs[rowbase + k];
                    #pragma unroll
                    for (int dw = 0; dw < 3; ++dw) {
                        #pragma unroll
                        for (int j = 0; j < 4; ++j) {
                            const float wv = wr[j][dh * 3 + dw];
                            #pragma unroll
                            for (int i = 0; i < 16; ++i)
                                acc[j][i] += xv[i + dw] * wv;
                        }
                    }
                }
            }
        }
    }

    // epilogue: coalesced float4 stores
    #pragma unroll
    for (int j = 0; j < 4; ++j) {
        const int co = cog * 4 + j;
        float* yp = y + ((((long long)co * D1 + a) * D2 + b) * HH + (h0 + r)) * WW
                      + wbase;
        #pragma unroll
        for (int i = 0; i < 16; i += 4) {
            float4 v = make_float4(acc[j][i], acc[j][i+1], acc[j][i+2], acc[j][i+3]);
            *reinterpret_cast<float4*>(yp + i) = v;
        }
    }
}

// ---------------------------------------------------------------------------
// Per-channel sum / sumsq (atomics into st[c*2], st[c*2+1]).
// grid = 32 channels * 64 parts, 256 threads, 8 float4 per thread.
// ---------------------------------------------------------------------------
__global__ __launch_bounds__(256)
void stats_kernel(const float* __restrict__ y, float* __restrict__ st)
{
    const int c    = blockIdx.x >> 6;
    const int part = blockIdx.x & 63;
    const int tid  = threadIdx.x;
    const float4* p =
        reinterpret_cast<const float4*>(y + (long long)c * SPATIAL) + part * 2048;
    float s = 0.f, s2 = 0.f;
    #pragma unroll
    for (int k = 0; k < 8; ++k) {
        float4 v = p[k * 256 + tid];
        s  += v.x + v.y + v.z + v.w;
        s2 += v.x * v.x + v.y * v.y + v.z * v.z + v.w * v.w;
    }
    #pragma unroll
    for (int off = 32; off > 0; off >>= 1) {
        s  += __shfl_down(s,  off, 64);
        s2 += __shfl_down(s2, off, 64);
    }
    __shared__ float red[8];
    const int wave = tid >> 6;
    if ((tid & 63) == 0) { red[wave * 2] = s; red[wave * 2 + 1] = s2; }
    __syncthreads();
    if (tid == 0) {
        float ts = red[0] + red[2] + red[4] + red[6];
        float t2 = red[1] + red[3] + red[5] + red[7];
        atomicAdd(&st[c * 2],     ts);
        atomicAdd(&st[c * 2 + 1], t2);
    }
}

// ---------------------------------------------------------------------------
// (x - mean) * rsqrt(var + eps), then leaky relu. float4, may be in-place.
// 131072 float4 per channel; 256-thread blocks stay within one channel.
// ---------------------------------------------------------------------------
__global__ __launch_bounds__(256)
void norm_leaky_kernel(const float* __restrict__ in, float* __restrict__ out,
                       const float* __restrict__ st)
{
    const long long idx4 = (long long)blockIdx.x * 256 + threadIdx.x;
    const int c = (int)(idx4 >> 17);   // / (SPATIAL/4)
    const float inv   = 1.f / (float)SPATIAL;
    const float mean  = st[c * 2] * inv;
    const float var   = st[c * 2 + 1] * inv - mean * mean;
    const float scale = rsqrtf(var + EPS);
    float4 v = reinterpret_cast<const float4*>(in)[idx4];
    float4 o;
    o.x = (v.x - mean) * scale; o.x = (o.x >= 0.f) ? o.x : NEG_SLOPE * o.x;
    o.y = (v.y - mean) * scale; o.y = (o.y >= 0.f) ? o.y : NEG_SLOPE * o.y;
    o.z = (v.z - mean) * scale; o.z = (o.z >= 0.f) ? o.z : NEG_SLOPE * o.z;
    o.w = (v.w - mean) * scale; o.w = (o.w >= 0.f) ? o.w : NEG_SLOPE * o.w;
    reinterpret_cast<float4*>(out)[idx4] = o;
}

// ---------------------------------------------------------------------------
extern "C" void kernel_launch(void* const* d_in, const int* in_sizes, int n_in,
                              void* d_out, int out_size, void* d_ws, size_t ws_size,
                              hipStream_t stream)
{
    const float* image = (const float*)d_in[0];
    const float* w1    = (const float*)d_in[1];
    const float* w2    = (const float*)d_in[2];
    float* out = (float*)d_out;

    float* y1 = (float*)d_ws;                                   // 64 MiB
    float* st = (float*)((char*)d_ws + (size_t)COUT * SPATIAL * sizeof(float));
    float* st1 = st;        // 64 floats
    float* st2 = st + 64;   // 64 floats

    hipMemsetAsync(st, 0, 128 * sizeof(float), stream);

    dim3 cgrid(8, 16, 8);   // (h-tile, b, a)
    conv4d_kernel<16><<<cgrid, 256, 0, stream>>>(image, w1, y1);
    stats_kernel<<<32 * 64, 256, 0, stream>>>(y1, st1);
    norm_leaky_kernel<<<16384, 256, 0, stream>>>(y1, y1, st1);  // in-place
    conv4d_kernel<32><<<cgrid, 256, 0, stream>>>(y1, w2, out);
    stats_kernel<<<32 * 64, 256, 0, stream>>>(out, st2);
    norm_leaky_kernel<<<16384, 256, 0, stream>>>(out, out, st2); // in-place
}

// Round 2
// 440.794 us; speedup vs baseline: 4.9652x; 4.9652x over previous
//
#include <hip/hip_runtime.h>

#define D1 8
#define D2 16
#define HH 64
#define WW 64
#define SPATIAL (D1*D2*HH*WW)   // 524288
#define EPS 1e-5f
#define NEG 0.2f

typedef unsigned short u16;
typedef __attribute__((ext_vector_type(8))) short s16x8;
typedef __attribute__((ext_vector_type(8))) unsigned short u16x8;
typedef __attribute__((ext_vector_type(4))) unsigned short u16x4;
typedef __attribute__((ext_vector_type(4))) float f32x4;

__device__ __forceinline__ u16 f2bf(float f) {
    unsigned int u = __builtin_bit_cast(unsigned int, f);
    return (u16)((u + 0x7FFFu + ((u >> 16) & 1u)) >> 16);   // RNE
}
__device__ __forceinline__ float bf2f(u16 u) {
    unsigned int v = ((unsigned int)u) << 16;
    return __builtin_bit_cast(float, v);
}
__device__ __forceinline__ float leaky(float x) {
    return x >= 0.f ? x : NEG * x;
}

// ---------------------------------------------------------------------------
// Weight transforms (bf16, MFMA-B-friendly layouts)
// w1t: [da][db][pair(5)][co(32)][k(32)]  k = s*16+ci packed 2 taps; pair4 upper=0
// w2t: [da][db][tap(9)][co(32)][ci(32)]
// ---------------------------------------------------------------------------
__global__ __launch_bounds__(256) void wtrans1(const float* __restrict__ w,
                                               u16* __restrict__ o) {
    int i = blockIdx.x * 256 + threadIdx.x;
    if (i >= 46080) return;
    int k  = i & 31;
    int co = (i >> 5) & 31;
    int pr = (i >> 10) % 5;
    int p  = (i >> 10) / 5;            // da*3+db
    int da = p / 3, db = p % 3;
    int t  = pr * 2 + (k >> 4);
    float v = 0.f;
    if (t < 9) {
        int ci = k & 15;
        int dh = t / 3, dw = t % 3;
        v = w[((((co * 16 + ci) * 3 + da) * 3 + db) * 3 + dh) * 3 + dw];
    }
    o[i] = f2bf(v);
}

__global__ __launch_bounds__(256) void wtrans2(const float* __restrict__ w,
                                               u16* __restrict__ o) {
    int i = blockIdx.x * 256 + threadIdx.x;
    if (i >= 82944) return;
    int ci = i & 31;
    int co = (i >> 5) & 31;
    int t  = (i >> 10) % 9;
    int p  = (i >> 10) / 9;
    int da = p / 3, db = p % 3, dh = t / 3, dw = t % 3;
    o[i] = f2bf(w[((((co * 32 + ci) * 3 + da) * 3 + db) * 3 + dh) * 3 + dw]);
}

// ---------------------------------------------------------------------------
// Image: [ci16][a][b][h][w] fp32  ->  [a][b][h][w][ci16] bf16 (channel-last)
// ---------------------------------------------------------------------------
__global__ __launch_bounds__(256) void imgtrans(const float* __restrict__ img,
                                                u16* __restrict__ o) {
    int p = blockIdx.x * 256 + threadIdx.x;   // 0..524287
    u16 r[16];
    #pragma unroll
    for (int c = 0; c < 16; ++c)
        r[c] = f2bf(img[(size_t)c * SPATIAL + p]);
    u16x8 lo, hi;
    #pragma unroll
    for (int j = 0; j < 8; ++j) { lo[j] = r[j]; hi[j] = r[8 + j]; }
    u16x8* dst = (u16x8*)(o + (size_t)p * 16);
    dst[0] = lo;
    dst[1] = hi;
}

// ---------------------------------------------------------------------------
// Conv1: Cin=16, taps packed 2-per-K-step (K=32). Input imgT channel-last bf16.
// Output y1 raw conv result, channel-last bf16 [pos][co32], + fused stats.
// LDS: 660 pos x 48B (stride 3 granules -> conflict-free phases 3p+g mod 8)
// ---------------------------------------------------------------------------
__global__ __launch_bounds__(256, 3)
void conv1_mfma(const u16* __restrict__ xT, const u16* __restrict__ w1t,
                u16* __restrict__ y1, float* __restrict__ st1)
{
    __shared__ __align__(16) u16 lds[660 * 24];   // 31680 B
    __shared__ float sred[64];

    const int tid  = threadIdx.x;
    const int h0   = blockIdx.x * 8;
    const int b    = blockIdx.y;
    const int a    = blockIdx.z;
    const int lane = tid & 63;
    const int wv   = tid >> 6;
    const int kq   = lane >> 4;      // 0..3
    const int m    = lane & 15;

    // zero pad-cols + OOB rows (block-constant across planes; done once)
    for (int e = tid; e < 660; e += 256) {
        int row = e / 66, col = e - row * 66;
        int h = h0 - 1 + row;
        if (col == 0 || col == 65 || h < 0 || h >= HH) {
            u16x8 z = (u16x8)0;
            *(u16x8*)&lds[e * 24]     = z;
            *(u16x8*)&lds[e * 24 + 8] = z;
        }
    }

    f32x4 acc[8][2];
    #pragma unroll
    for (int i = 0; i < 8; ++i)
        #pragma unroll
        for (int nt = 0; nt < 2; ++nt)
            acc[i][nt] = (f32x4)0.f;

    for (int da = 0; da < 3; ++da) {
        int ap = a + da - 1;
        if (ap < 0 || ap >= D1) continue;
        for (int db = 0; db < 3; ++db) {
            int bp = b + db - 1;
            if (bp < 0 || bp >= D2) continue;

            __syncthreads();
            // stage plane: 1320 interior granules (g = tid&1 fixed)
            {
                const u16* src = xT + (size_t)(ap * D2 + bp) * (HH * WW * 16);
                #pragma unroll
                for (int i = 0; i < 6; ++i) {
                    int gi = tid + (i << 8);
                    if (gi >= 1320) break;
                    int pos = gi >> 1, g = gi & 1;
                    int row = pos / 66, col = pos - row * 66;
                    int h = h0 - 1 + row, w = col - 1;
                    if (col >= 1 && col <= 64 && h >= 0 && h < HH) {
                        u16x8 v = *(const u16x8*)(src + (h * WW + w) * 16 + g * 8);
                        *(u16x8*)&lds[pos * 24 + g * 8] = v;
                    }
                }
            }
            __syncthreads();

            const u16* wbase = w1t + (da * 3 + db) * 5 * 1024;
            for (int pr = 0; pr < 5; ++pr) {
                s16x8 bf0 = *(const s16x8*)(wbase + pr * 1024 + m * 32 + kq * 8);
                s16x8 bf1 = *(const s16x8*)(wbase + pr * 1024 + (m + 16) * 32 + kq * 8);
                int s0 = pr * 2 + (kq >> 1);
                if (s0 > 8) s0 = 8;               // pair4 upper half: B rows are 0
                int g  = kq & 1;
                int dh = s0 / 3, dw = s0 - dh * 3;
                #pragma unroll
                for (int i = 0; i < 8; ++i) {
                    int mt   = wv * 8 + i;
                    int r    = mt >> 2;
                    int wseg = (mt & 3) << 4;
                    int pos  = (r + dh) * 66 + wseg + dw + m;
                    s16x8 af = *(const s16x8*)&lds[pos * 24 + g * 8];
                    acc[i][0] = __builtin_amdgcn_mfma_f32_16x16x32_bf16(af, bf0, acc[i][0], 0, 0, 0);
                    acc[i][1] = __builtin_amdgcn_mfma_f32_16x16x32_bf16(af, bf1, acc[i][1], 0, 0, 0);
                }
            }
        }
    }

    // epilogue: channel-last bf16 store + fused per-channel stats
    if (tid < 64) sred[tid] = 0.f;
    __syncthreads();

    float s[2] = {0.f, 0.f}, s2[2] = {0.f, 0.f};
    const size_t plane_out = (size_t)(a * D2 + b) * (HH * WW);
    #pragma unroll
    for (int i = 0; i < 8; ++i) {
        int mt   = wv * 8 + i;
        int r    = mt >> 2;
        int wseg = (mt & 3) << 4;
        int h    = h0 + r;
        int w0   = wseg + kq * 4;
        #pragma unroll
        for (int nt = 0; nt < 2; ++nt) {
            int co = m + nt * 16;
            #pragma unroll
            for (int reg = 0; reg < 4; ++reg) {
                float v = acc[i][nt][reg];
                s[nt]  += v;
                s2[nt] += v * v;
                y1[(plane_out + h * WW + (w0 + reg)) * 32 + co] = f2bf(v);
            }
        }
    }
    #pragma unroll
    for (int nt = 0; nt < 2; ++nt) {
        s[nt]  += __shfl_xor(s[nt], 16);  s[nt]  += __shfl_xor(s[nt], 32);
        s2[nt] += __shfl_xor(s2[nt], 16); s2[nt] += __shfl_xor(s2[nt], 32);
    }
    if (kq == 0) {
        atomicAdd(&sred[m * 2],            s[0]);
        atomicAdd(&sred[m * 2 + 1],        s2[0]);
        atomicAdd(&sred[(m + 16) * 2],     s[1]);
        atomicAdd(&sred[(m + 16) * 2 + 1], s2[1]);
    }
    __syncthreads();
    if (tid < 64) atomicAdd(&st1[tid], sred[tid]);
}

// ---------------------------------------------------------------------------
// Conv2: Cin=32 (K=32 per tap). Staging fuses instance-norm + leaky from st1.
// Output y2 raw conv, channel-FIRST bf16, + fused stats.
// LDS: 660 pos x 80B (stride 5 granules -> conflict-free phases 5p+q mod 8)
// ---------------------------------------------------------------------------
__global__ __launch_bounds__(256, 3)
void conv2_mfma(const u16* __restrict__ y1, const u16* __restrict__ w2t,
                const float* __restrict__ st1, u16* __restrict__ y2,
                float* __restrict__ st2)
{
    __shared__ __align__(16) u16 lds[660 * 40];   // 52800 B
    __shared__ float sred[64];

    const int tid  = threadIdx.x;
    const int h0   = blockIdx.x * 8;
    const int b    = blockIdx.y;
    const int a    = blockIdx.z;
    const int lane = tid & 63;
    const int wv   = tid >> 6;
    const int kq   = lane >> 4;
    const int m    = lane & 15;
    const int q    = tid & 3;        // staging ci-quarter (fixed per thread)

    // per-thread norm constants for its 8 channels
    float mean[8], scl[8];
    const float invN = 1.f / (float)SPATIAL;
    #pragma unroll
    for (int j = 0; j < 8; ++j) {
        int ci  = q * 8 + j;
        float mu = st1[ci * 2] * invN;
        float va = st1[ci * 2 + 1] * invN - mu * mu;
        mean[j] = mu;
        scl[j]  = rsqrtf(va + EPS);
    }

    // zero pad-cols + OOB rows once
    for (int e = tid; e < 660; e += 256) {
        int row = e / 66, col = e - row * 66;
        int h = h0 - 1 + row;
        if (col == 0 || col == 65 || h < 0 || h >= HH) {
            u16x8 z = (u16x8)0;
            #pragma unroll
            for (int g = 0; g < 4; ++g)
                *(u16x8*)&lds[e * 40 + g * 8] = z;
        }
    }

    f32x4 acc[8][2];
    #pragma unroll
    for (int i = 0; i < 8; ++i)
        #pragma unroll
        for (int nt = 0; nt < 2; ++nt)
            acc[i][nt] = (f32x4)0.f;

    for (int da = 0; da < 3; ++da) {
        int ap = a + da - 1;
        if (ap < 0 || ap >= D1) continue;
        for (int db = 0; db < 3; ++db) {
            int bp = b + db - 1;
            if (bp < 0 || bp >= D2) continue;

            __syncthreads();
            // stage plane with fused norm+leaky: 2640 interior granules
            {
                const u16* src = y1 + (size_t)(ap * D2 + bp) * (HH * WW * 32);
                #pragma unroll
                for (int i = 0; i < 11; ++i) {
                    int gi = tid + (i << 8);
                    if (gi >= 2640) break;
                    int pos = gi >> 2;
                    int row = pos / 66, col = pos - row * 66;
                    int h = h0 - 1 + row, w = col - 1;
                    if (col >= 1 && col <= 64 && h >= 0 && h < HH) {
                        u16x8 v = *(const u16x8*)(src + (h * WW + w) * 32 + q * 8);
                        u16x8 o;
                        #pragma unroll
                        for (int j = 0; j < 8; ++j) {
                            float x = (bf2f(v[j]) - mean[j]) * scl[j];
                            o[j] = f2bf(leaky(x));
                        }
                        *(u16x8*)&lds[pos * 40 + q * 8] = o;
                    }
                }
            }
            __syncthreads();

            const u16* wbase = w2t + (da * 3 + db) * 9 * 1024;
            for (int t = 0; t < 9; ++t) {
                s16x8 bf0 = *(const s16x8*)(wbase + t * 1024 + m * 32 + kq * 8);
                s16x8 bf1 = *(const s16x8*)(wbase + t * 1024 + (m + 16) * 32 + kq * 8);
                int dh = t / 3, dw = t - dh * 3;
                #pragma unroll
                for (int i = 0; i < 8; ++i) {
                    int mt   = wv * 8 + i;
                    int r    = mt >> 2;
                    int wseg = (mt & 3) << 4;
                    int pos  = (r + dh) * 66 + wseg + dw + m;
                    s16x8 af = *(const s16x8*)&lds[pos * 40 + kq * 8];
                    acc[i][0] = __builtin_amdgcn_mfma_f32_16x16x32_bf16(af, bf0, acc[i][0], 0, 0, 0);
                    acc[i][1] = __builtin_amdgcn_mfma_f32_16x16x32_bf16(af, bf1, acc[i][1], 0, 0, 0);
                }
            }
        }
    }

    // epilogue: channel-first bf16 (4 consecutive w per store) + fused stats
    if (tid < 64) sred[tid] = 0.f;
    __syncthreads();

    float s[2] = {0.f, 0.f}, s2[2] = {0.f, 0.f};
    #pragma unroll
    for (int i = 0; i < 8; ++i) {
        int mt   = wv * 8 + i;
        int r    = mt >> 2;
        int wseg = (mt & 3) << 4;
        int h    = h0 + r;
        int w0   = wseg + kq * 4;
        #pragma unroll
        for (int nt = 0; nt < 2; ++nt) {
            int co = m + nt * 16;
            u16x4 pk;
            #pragma unroll
            for (int reg = 0; reg < 4; ++reg) {
                float v = acc[i][nt][reg];
                s[nt]  += v;
                s2[nt] += v * v;
                pk[reg] = f2bf(v);
            }
            size_t off = ((size_t)(co * D1 + a) * D2 + b) * (HH * WW) + h * WW + w0;
            *(u16x4*)(y2 + off) = pk;
        }
    }
    #pragma unroll
    for (int nt = 0; nt < 2; ++nt) {
        s[nt]  += __shfl_xor(s[nt], 16);  s[nt]  += __shfl_xor(s[nt], 32);
        s2[nt] += __shfl_xor(s2[nt], 16); s2[nt] += __shfl_xor(s2[nt], 32);
    }
    if (kq == 0) {
        atomicAdd(&sred[m * 2],            s[0]);
        atomicAdd(&sred[m * 2 + 1],        s2[0]);
        atomicAdd(&sred[(m + 16) * 2],     s[1]);
        atomicAdd(&sred[(m + 16) * 2 + 1], s2[1]);
    }
    __syncthreads();
    if (tid < 64) atomicAdd(&st2[tid], sred[tid]);
}

// ---------------------------------------------------------------------------
// Final: norm + leaky, bf16 channel-first -> fp32 channel-first d_out
// ---------------------------------------------------------------------------
__global__ __launch_bounds__(256)
void norm2_kernel(const u16* __restrict__ y2, const float* __restrict__ st2,
                  float* __restrict__ out)
{
    size_t i4 = (size_t)blockIdx.x * 256 + threadIdx.x;   // 4,194,304 groups
    int c = (int)(i4 >> 17);                              // SPATIAL/4 = 131072
    const float invN = 1.f / (float)SPATIAL;
    float mu = st2[c * 2] * invN;
    float va = st2[c * 2 + 1] * invN - mu * mu;
    float sc = rsqrtf(va + EPS);
    u16x4 v = *(const u16x4*)(y2 + i4 * 4);
    float4 o;
    o.x = leaky((bf2f(v[0]) - mu) * sc);
    o.y = leaky((bf2f(v[1]) - mu) * sc);
    o.z = leaky((bf2f(v[2]) - mu) * sc);
    o.w = leaky((bf2f(v[3]) - mu) * sc);
    *(float4*)(out + i4 * 4) = o;
}

// ---------------------------------------------------------------------------
extern "C" void kernel_launch(void* const* d_in, const int* in_sizes, int n_in,
                              void* d_out, int out_size, void* d_ws, size_t ws_size,
                              hipStream_t stream)
{
    const float* image = (const float*)d_in[0];
    const float* w1    = (const float*)d_in[1];
    const float* w2    = (const float*)d_in[2];
    float* out = (float*)d_out;

    // ws: [0,32MB) imgT (reused as y2) | [32MB,64MB) y1 | [64MB,+512B) stats
    u16*   imgT = (u16*)d_ws;
    u16*   y1   = (u16*)((char*)d_ws + 33554432);
    u16*   y2   = imgT;
    float* st   = (float*)((char*)d_ws + 67108864);
    float* st1  = st;
    float* st2  = st + 64;

    // weight tables live in d_out's tail; dead before norm2 overwrites d_out
    u16* w1t = (u16*)((char*)d_out + 66850816);   // 46080 bf16
    u16* w2t = (u16*)((char*)d_out + 66942976);   // 82944 bf16

    hipMemsetAsync(st, 0, 512, stream);
    wtrans1<<<180, 256, 0, stream>>>(w1, w1t);
    wtrans2<<<324, 256, 0, stream>>>(w2, w2t);
    imgtrans<<<2048, 256, 0, stream>>>(image, imgT);

    dim3 g(8, 16, 8);   // (h-tile, b, a)
    conv1_mfma<<<g, 256, 0, stream>>>(imgT, w1t, y1, st1);
    conv2_mfma<<<g, 256, 0, stream>>>(y1, w2t, st1, y2, st2);
    norm2_kernel<<<16384, 256, 0, stream>>>(y2, st2, out);
}

// Round 3
// 314.908 us; speedup vs baseline: 6.9501x; 1.3998x over previous
//
#include <hip/hip_runtime.h>

#define D1 8
#define D2 16
#define HH 64
#define WW 64
#define SPATIAL (D1*D2*HH*WW)   // 524288
#define EPS 1e-5f
#define NEG 0.2f

typedef unsigned short u16;
typedef __attribute__((ext_vector_type(8))) short s16x8;
typedef __attribute__((ext_vector_type(8))) unsigned short u16x8;
typedef __attribute__((ext_vector_type(4))) unsigned short u16x4;
typedef __attribute__((ext_vector_type(4))) float f32x4;

__device__ __forceinline__ u16 f2bf(float f) {
    unsigned int u = __builtin_bit_cast(unsigned int, f);
    return (u16)((u + 0x7FFFu + ((u >> 16) & 1u)) >> 16);   // RNE
}
__device__ __forceinline__ float bf2f(u16 u) {
    unsigned int v = ((unsigned int)u) << 16;
    return __builtin_bit_cast(float, v);
}
__device__ __forceinline__ float leaky(float x) {
    return x >= 0.f ? x : NEG * x;
}

// XCD swizzle: all 8 h-tiles of one (a,b) land on one XCD, consecutively.
__device__ __forceinline__ void decode_block(int flat, int& a, int& b, int& h0) {
    int xcd  = flat & 7;
    int slot = flat >> 3;
    int ht   = slot & 7;
    a        = (slot >> 3) & 7;
    b        = ((slot >> 6) << 3) | xcd;
    h0       = ht * 8;
}

// ---------------------------------------------------------------------------
// Weight transforms (bf16, MFMA-B-friendly layouts)
// w1t: [p(9)][pair(5)][co(32)][k(32)]  k = s*16+ci packed 2 taps; pair4 upper=0
// w2t: [p(9)][tap(9)][co(32)][ci(32)]
// ---------------------------------------------------------------------------
__global__ __launch_bounds__(256) void wtrans1(const float* __restrict__ w,
                                               u16* __restrict__ o) {
    int i = blockIdx.x * 256 + threadIdx.x;
    if (i >= 46080) return;
    int k  = i & 31;
    int co = (i >> 5) & 31;
    int pr = (i >> 10) % 5;
    int p  = (i >> 10) / 5;            // da*3+db
    int da = p / 3, db = p % 3;
    int t  = pr * 2 + (k >> 4);
    float v = 0.f;
    if (t < 9) {
        int ci = k & 15;
        int dh = t / 3, dw = t % 3;
        v = w[((((co * 16 + ci) * 3 + da) * 3 + db) * 3 + dh) * 3 + dw];
    }
    o[i] = f2bf(v);
}

__global__ __launch_bounds__(256) void wtrans2(const float* __restrict__ w,
                                               u16* __restrict__ o) {
    int i = blockIdx.x * 256 + threadIdx.x;
    if (i >= 82944) return;
    int ci = i & 31;
    int co = (i >> 5) & 31;
    int t  = (i >> 10) % 9;
    int p  = (i >> 10) / 9;
    int da = p / 3, db = p % 3, dh = t / 3, dw = t % 3;
    o[i] = f2bf(w[((((co * 32 + ci) * 3 + da) * 3 + db) * 3 + dh) * 3 + dw]);
}

// ---------------------------------------------------------------------------
// Image: [ci16][spatial] fp32 -> [spatial][ci16] bf16 (channel-last)
// ---------------------------------------------------------------------------
__global__ __launch_bounds__(256) void imgtrans(const float* __restrict__ img,
                                                u16* __restrict__ o) {
    int p = blockIdx.x * 256 + threadIdx.x;
    u16 r[16];
    #pragma unroll
    for (int c = 0; c < 16; ++c)
        r[c] = f2bf(img[(size_t)c * SPATIAL + p]);
    u16x8 lo, hi;
    #pragma unroll
    for (int j = 0; j < 8; ++j) { lo[j] = r[j]; hi[j] = r[8 + j]; }
    u16x8* dst = (u16x8*)(o + (size_t)p * 16);
    dst[0] = lo;
    dst[1] = hi;
}

// ---------------------------------------------------------------------------
// Conv1: Cin=16, taps packed 2-per-K-step. In: imgT channel-last bf16.
// Out: y1 raw conv, channel-last bf16 [pos][co32], + fused stats.
// LDS pos stride 24 u16 (48B): (3*pos+g)%8 uniform -> conflict-free.
// Register-prefetch pipeline over valid (da,db) planes.
// ---------------------------------------------------------------------------
__global__ __launch_bounds__(256, 2)
void conv1_mfma(const u16* __restrict__ xT, const u16* __restrict__ w1t,
                u16* __restrict__ y1, float* __restrict__ st1)
{
    __shared__ __align__(16) u16 lds[660 * 24];   // 31680 B
    __shared__ float sred[64];

    const int tid = threadIdx.x;
    int a, b, h0;
    decode_block(blockIdx.x, a, b, h0);
    const int lane = tid & 63;
    const int wv   = tid >> 6;
    const int kq   = lane >> 4;
    const int m    = lane & 15;

    // valid-plane bitmask (block-uniform)
    unsigned pm = 0;
    #pragma unroll
    for (int p = 0; p < 9; ++p) {
        int ap = a + p / 3 - 1, bp = b + p % 3 - 1;
        if (ap >= 0 && ap < D1 && bp >= 0 && bp < D2) pm |= 1u << p;
    }

    // plane-invariant staging offsets (6 granules/thread max)
    const int p0 = tid >> 1, g = tid & 1;
    unsigned vmask = 0;
    int goff[6];
    #pragma unroll
    for (int k = 0; k < 6; ++k) {
        int pos = p0 + 128 * k;
        int row = pos / 66, col = pos - row * 66;
        int h = h0 - 1 + row, w = col - 1;
        bool v = (pos < 660) && col >= 1 && col <= 64 && h >= 0 && h < HH;
        goff[k] = v ? (h * WW + w) * 16 + g * 8 : 0;
        vmask |= (unsigned)v << k;
    }
    const int lbase = p0 * 24 + g * 8;

    // zero pad/OOB LDS cells once
    for (int e = tid; e < 660; e += 256) {
        int row = e / 66, col = e - row * 66;
        int h = h0 - 1 + row;
        if (col == 0 || col == 65 || h < 0 || h >= HH) {
            u16x8 z = (u16x8)0;
            *(u16x8*)&lds[e * 24]     = z;
            *(u16x8*)&lds[e * 24 + 8] = z;
        }
    }

    f32x4 acc[8][2];
    #pragma unroll
    for (int i = 0; i < 8; ++i)
        #pragma unroll
        for (int nt = 0; nt < 2; ++nt)
            acc[i][nt] = (f32x4)0.f;

    int p = 0;
    while (!((pm >> p) & 1)) ++p;

    u16x8 pf[6];
    {
        int ap = a + p / 3 - 1, bp = b + p % 3 - 1;
        const u16* src = xT + (size_t)(ap * D2 + bp) * (HH * WW * 16);
        #pragma unroll
        for (int k = 0; k < 6; ++k)
            if ((vmask >> k) & 1) pf[k] = *(const u16x8*)(src + goff[k]);
    }

    while (p < 9) {
        int pn = p + 1;
        while (pn < 9 && !((pm >> pn) & 1)) ++pn;

        #pragma unroll
        for (int k = 0; k < 6; ++k)
            if ((vmask >> k) & 1) *(u16x8*)&lds[lbase + k * 3072] = pf[k];
        __syncthreads();

        if (pn < 9) {   // prefetch next plane during MFMA phase
            int ap = a + pn / 3 - 1, bp = b + pn % 3 - 1;
            const u16* src = xT + (size_t)(ap * D2 + bp) * (HH * WW * 16);
            #pragma unroll
            for (int k = 0; k < 6; ++k)
                if ((vmask >> k) & 1) pf[k] = *(const u16x8*)(src + goff[k]);
        }

        const u16* wbase = w1t + p * 5120;
        for (int pr = 0; pr < 5; ++pr) {
            s16x8 bf0 = *(const s16x8*)(wbase + pr * 1024 + m * 32 + kq * 8);
            s16x8 bf1 = *(const s16x8*)(wbase + pr * 1024 + (m + 16) * 32 + kq * 8);
            int s0 = pr * 2 + (kq >> 1);
            if (s0 > 8) s0 = 8;               // pair4 upper half: B rows are 0
            int gg = kq & 1;
            int dh = s0 / 3, dw = s0 - dh * 3;
            #pragma unroll
            for (int i = 0; i < 8; ++i) {
                int mt   = wv * 8 + i;
                int r    = mt >> 2;
                int wseg = (mt & 3) << 4;
                int pos  = (r + dh) * 66 + wseg + dw + m;
                s16x8 af = *(const s16x8*)&lds[pos * 24 + gg * 8];
                acc[i][0] = __builtin_amdgcn_mfma_f32_16x16x32_bf16(af, bf0, acc[i][0], 0, 0, 0);
                acc[i][1] = __builtin_amdgcn_mfma_f32_16x16x32_bf16(af, bf1, acc[i][1], 0, 0, 0);
            }
        }
        __syncthreads();
        p = pn;
    }

    // epilogue: channel-last bf16 store + fused per-channel stats
    if (tid < 64) sred[tid] = 0.f;
    __syncthreads();

    float s[2] = {0.f, 0.f}, s2[2] = {0.f, 0.f};
    const size_t plane_out = (size_t)(a * D2 + b) * (HH * WW);
    #pragma unroll
    for (int i = 0; i < 8; ++i) {
        int mt   = wv * 8 + i;
        int r    = mt >> 2;
        int wseg = (mt & 3) << 4;
        int h    = h0 + r;
        int w0   = wseg + kq * 4;
        #pragma unroll
        for (int nt = 0; nt < 2; ++nt) {
            int co = m + nt * 16;
            #pragma unroll
            for (int reg = 0; reg < 4; ++reg) {
                float v = acc[i][nt][reg];
                s[nt]  += v;
                s2[nt] += v * v;
                y1[(plane_out + h * WW + (w0 + reg)) * 32 + co] = f2bf(v);
            }
        }
    }
    #pragma unroll
    for (int nt = 0; nt < 2; ++nt) {
        s[nt]  += __shfl_xor(s[nt], 16);  s[nt]  += __shfl_xor(s[nt], 32);
        s2[nt] += __shfl_xor(s2[nt], 16); s2[nt] += __shfl_xor(s2[nt], 32);
    }
    if (kq == 0) {
        atomicAdd(&sred[m * 2],            s[0]);
        atomicAdd(&sred[m * 2 + 1],        s2[0]);
        atomicAdd(&sred[(m + 16) * 2],     s[1]);
        atomicAdd(&sred[(m + 16) * 2 + 1], s2[1]);
    }
    __syncthreads();
    if (tid < 64) atomicAdd(&st1[tid], sred[tid]);
}

// ---------------------------------------------------------------------------
// norm1: in-place instance-norm + leaky on y1 (channel-last bf16).
// 2048 blocks x 256 threads x 4 granules.
// ---------------------------------------------------------------------------
__global__ __launch_bounds__(256)
void norm1_kernel(u16* __restrict__ y1, const float* __restrict__ st1)
{
    const int tid = threadIdx.x;
    const int q   = tid & 3;
    const float invN = 1.f / (float)SPATIAL;
    float mean[8], scl[8];
    #pragma unroll
    for (int j = 0; j < 8; ++j) {
        int ci  = q * 8 + j;
        float mu = st1[ci * 2] * invN;
        float va = st1[ci * 2 + 1] * invN - mu * mu;
        mean[j] = mu;
        scl[j]  = rsqrtf(va + EPS);
    }
    #pragma unroll
    for (int j4 = 0; j4 < 4; ++j4) {
        size_t gidx = (size_t)blockIdx.x * 1024 + j4 * 256 + tid;
        u16x8* ptr = (u16x8*)(y1 + gidx * 8);
        u16x8 v = *ptr;
        u16x8 o;
        #pragma unroll
        for (int j = 0; j < 8; ++j)
            o[j] = f2bf(leaky((bf2f(v[j]) - mean[j]) * scl[j]));
        *ptr = o;
    }
}

// ---------------------------------------------------------------------------
// Conv2: Cin=32, pure-copy staging (y1 already normalized), reg prefetch.
// Out: y2 raw conv, channel-FIRST bf16, + fused stats.
// LDS pos stride 40 u16 (80B): (5*pos+q)%8 uniform -> conflict-free.
// ---------------------------------------------------------------------------
__global__ __launch_bounds__(256, 2)
void conv2_mfma(const u16* __restrict__ y1, const u16* __restrict__ w2t,
                u16* __restrict__ y2, float* __restrict__ st2)
{
    __shared__ __align__(16) u16 lds[660 * 40];   // 52800 B
    __shared__ float sred[64];

    const int tid = threadIdx.x;
    int a, b, h0;
    decode_block(blockIdx.x, a, b, h0);
    const int lane = tid & 63;
    const int wv   = tid >> 6;
    const int kq   = lane >> 4;
    const int m    = lane & 15;

    unsigned pm = 0;
    #pragma unroll
    for (int p = 0; p < 9; ++p) {
        int ap = a + p / 3 - 1, bp = b + p % 3 - 1;
        if (ap >= 0 && ap < D1 && bp >= 0 && bp < D2) pm |= 1u << p;
    }

    // plane-invariant staging offsets (11 granules/thread max)
    const int p0 = tid >> 2, q = tid & 3;
    unsigned vmask = 0;
    int goff[11];
    #pragma unroll
    for (int k = 0; k < 11; ++k) {
        int pos = p0 + 64 * k;
        int row = pos / 66, col = pos - row * 66;
        int h = h0 - 1 + row, w = col - 1;
        bool v = (pos < 660) && col >= 1 && col <= 64 && h >= 0 && h < HH;
        goff[k] = v ? (h * WW + w) * 32 + q * 8 : 0;
        vmask |= (unsigned)v << k;
    }
    const int lbase = p0 * 40 + q * 8;

    for (int e = tid; e < 660; e += 256) {
        int row = e / 66, col = e - row * 66;
        int h = h0 - 1 + row;
        if (col == 0 || col == 65 || h < 0 || h >= HH) {
            u16x8 z = (u16x8)0;
            #pragma unroll
            for (int gg = 0; gg < 4; ++gg)
                *(u16x8*)&lds[e * 40 + gg * 8] = z;
        }
    }

    f32x4 acc[8][2];
    #pragma unroll
    for (int i = 0; i < 8; ++i)
        #pragma unroll
        for (int nt = 0; nt < 2; ++nt)
            acc[i][nt] = (f32x4)0.f;

    int p = 0;
    while (!((pm >> p) & 1)) ++p;

    u16x8 pf[11];
    {
        int ap = a + p / 3 - 1, bp = b + p % 3 - 1;
        const u16* src = y1 + (size_t)(ap * D2 + bp) * (HH * WW * 32);
        #pragma unroll
        for (int k = 0; k < 11; ++k)
            if ((vmask >> k) & 1) pf[k] = *(const u16x8*)(src + goff[k]);
    }

    while (p < 9) {
        int pn = p + 1;
        while (pn < 9 && !((pm >> pn) & 1)) ++pn;

        #pragma unroll
        for (int k = 0; k < 11; ++k)
            if ((vmask >> k) & 1) *(u16x8*)&lds[lbase + k * 2560] = pf[k];
        __syncthreads();

        if (pn < 9) {   // prefetch next plane during MFMA phase
            int ap = a + pn / 3 - 1, bp = b + pn % 3 - 1;
            const u16* src = y1 + (size_t)(ap * D2 + bp) * (HH * WW * 32);
            #pragma unroll
            for (int k = 0; k < 11; ++k)
                if ((vmask >> k) & 1) pf[k] = *(const u16x8*)(src + goff[k]);
        }

        const u16* wbase = w2t + p * 9216;
        for (int t = 0; t < 9; ++t) {
            s16x8 bf0 = *(const s16x8*)(wbase + t * 1024 + m * 32 + kq * 8);
            s16x8 bf1 = *(const s16x8*)(wbase + t * 1024 + (m + 16) * 32 + kq * 8);
            int dh = t / 3, dw = t - dh * 3;
            #pragma unroll
            for (int i = 0; i < 8; ++i) {
                int mt   = wv * 8 + i;
                int r    = mt >> 2;
                int wseg = (mt & 3) << 4;
                int pos  = (r + dh) * 66 + wseg + dw + m;
                s16x8 af = *(const s16x8*)&lds[pos * 40 + kq * 8];
                acc[i][0] = __builtin_amdgcn_mfma_f32_16x16x32_bf16(af, bf0, acc[i][0], 0, 0, 0);
                acc[i][1] = __builtin_amdgcn_mfma_f32_16x16x32_bf16(af, bf1, acc[i][1], 0, 0, 0);
            }
        }
        __syncthreads();
        p = pn;
    }

    // epilogue: channel-first bf16 + fused stats
    if (tid < 64) sred[tid] = 0.f;
    __syncthreads();

    float s[2] = {0.f, 0.f}, s2[2] = {0.f, 0.f};
    #pragma unroll
    for (int i = 0; i < 8; ++i) {
        int mt   = wv * 8 + i;
        int r    = mt >> 2;
        int wseg = (mt & 3) << 4;
        int h    = h0 + r;
        int w0   = wseg + kq * 4;
        #pragma unroll
        for (int nt = 0; nt < 2; ++nt) {
            int co = m + nt * 16;
            u16x4 pk;
            #pragma unroll
            for (int reg = 0; reg < 4; ++reg) {
                float v = acc[i][nt][reg];
                s[nt]  += v;
                s2[nt] += v * v;
                pk[reg] = f2bf(v);
            }
            size_t off = ((size_t)(co * D1 + a) * D2 + b) * (HH * WW) + h * WW + w0;
            *(u16x4*)(y2 + off) = pk;
        }
    }
    #pragma unroll
    for (int nt = 0; nt < 2; ++nt) {
        s[nt]  += __shfl_xor(s[nt], 16);  s[nt]  += __shfl_xor(s[nt], 32);
        s2[nt] += __shfl_xor(s2[nt], 16); s2[nt] += __shfl_xor(s2[nt], 32);
    }
    if (kq == 0) {
        atomicAdd(&sred[m * 2],            s[0]);
        atomicAdd(&sred[m * 2 + 1],        s2[0]);
        atomicAdd(&sred[(m + 16) * 2],     s[1]);
        atomicAdd(&sred[(m + 16) * 2 + 1], s2[1]);
    }
    __syncthreads();
    if (tid < 64) atomicAdd(&st2[tid], sred[tid]);
}

// ---------------------------------------------------------------------------
// Final: norm + leaky, bf16 channel-first -> fp32 channel-first d_out
// ---------------------------------------------------------------------------
__global__ __launch_bounds__(256)
void norm2_kernel(const u16* __restrict__ y2, const float* __restrict__ st2,
                  float* __restrict__ out)
{
    size_t i4 = (size_t)blockIdx.x * 256 + threadIdx.x;
    int c = (int)(i4 >> 17);
    const float invN = 1.f / (float)SPATIAL;
    float mu = st2[c * 2] * invN;
    float va = st2[c * 2 + 1] * invN - mu * mu;
    float sc = rsqrtf(va + EPS);
    u16x4 v = *(const u16x4*)(y2 + i4 * 4);
    float4 o;
    o.x = leaky((bf2f(v[0]) - mu) * sc);
    o.y = leaky((bf2f(v[1]) - mu) * sc);
    o.z = leaky((bf2f(v[2]) - mu) * sc);
    o.w = leaky((bf2f(v[3]) - mu) * sc);
    *(float4*)(out + i4 * 4) = o;
}

// ---------------------------------------------------------------------------
extern "C" void kernel_launch(void* const* d_in, const int* in_sizes, int n_in,
                              void* d_out, int out_size, void* d_ws, size_t ws_size,
                              hipStream_t stream)
{
    const float* image = (const float*)d_in[0];
    const float* w1    = (const float*)d_in[1];
    const float* w2    = (const float*)d_in[2];
    float* out = (float*)d_out;

    // ws: [0,32MB) imgT (reused as y2) | [32MB,64MB) y1 | [64MB,+512B) stats
    u16*   imgT = (u16*)d_ws;
    u16*   y1   = (u16*)((char*)d_ws + 33554432);
    u16*   y2   = imgT;
    float* st   = (float*)((char*)d_ws + 67108864);
    float* st1  = st;
    float* st2  = st + 64;

    // weight tables live in d_out's tail; dead before norm2 overwrites d_out
    u16* w1t = (u16*)((char*)d_out + 66850816);   // 46080 bf16
    u16* w2t = (u16*)((char*)d_out + 66942976);   // 82944 bf16

    hipMemsetAsync(st, 0, 512, stream);
    wtrans1<<<180, 256, 0, stream>>>(w1, w1t);
    wtrans2<<<324, 256, 0, stream>>>(w2, w2t);
    imgtrans<<<2048, 256, 0, stream>>>(image, imgT);

    conv1_mfma<<<1024, 256, 0, stream>>>(imgT, w1t, y1, st1);
    norm1_kernel<<<2048, 256, 0, stream>>>(y1, st1);
    conv2_mfma<<<1024, 256, 0, stream>>>(y1, w2t, y2, st2);
    norm2_kernel<<<16384, 256, 0, stream>>>(y2, st2, out);
}

// Round 4
// 277.206 us; speedup vs baseline: 7.8953x; 1.1360x over previous
//
#include <hip/hip_runtime.h>

#define D1 8
#define D2 16
#define HH 64
#define WW 64
#define SPATIAL (D1*D2*HH*WW)   // 524288
#define EPS 1e-5f
#define NEG 0.2f

typedef unsigned short u16;
typedef __attribute__((ext_vector_type(8))) short s16x8;
typedef __attribute__((ext_vector_type(8))) unsigned short u16x8;
typedef __attribute__((ext_vector_type(4))) unsigned short u16x4;
typedef __attribute__((ext_vector_type(4))) float f32x4;

__device__ __forceinline__ u16 f2bf(float f) {
    unsigned int u = __builtin_bit_cast(unsigned int, f);
    return (u16)((u + 0x7FFFu + ((u >> 16) & 1u)) >> 16);   // RNE
}
__device__ __forceinline__ float bf2f(u16 u) {
    unsigned int v = ((unsigned int)u) << 16;
    return __builtin_bit_cast(float, v);
}
__device__ __forceinline__ float leaky(float x) {
    return x >= 0.f ? x : NEG * x;
}

// XCD swizzle v2: b-PAIR per XCD (db-halo L2 reuse) + all h-tiles/a consecutive.
// flat = xcd(3) | [ht(3) | b0(1) | a(3)]
__device__ __forceinline__ void decode_block(int flat, int& a, int& b, int& h0) {
    int xcd  = flat & 7;
    int slot = flat >> 3;
    int ht   = slot & 7;
    int b0   = (slot >> 3) & 1;
    a        = (slot >> 4) & 7;
    b        = xcd * 2 + b0;
    h0       = ht * 8;
}

// ---------------------------------------------------------------------------
// Weight transforms (bf16, MFMA-B-friendly layouts)
// w1t: [p(9)][dh(3)][grp(2)][co(32)][k(32)]
//      grp0: k = dw(0/1)*16 + ci(16); grp1: k = ci(16) for dw=2, upper 16 = 0
// w2t: [p(9)][tap(9)][co(32)][ci(32)]
// ---------------------------------------------------------------------------
__global__ __launch_bounds__(256) void wtrans1(const float* __restrict__ w,
                                               u16* __restrict__ o) {
    int i = blockIdx.x * 256 + threadIdx.x;
    if (i >= 55296) return;
    int k    = i & 31;
    int co   = (i >> 5) & 31;
    int grp  = (i >> 10) & 1;
    int rest = i >> 11;           // 0..26 = p*3+dh
    int dh   = rest % 3;
    int p    = rest / 3;
    int da = p / 3, db = p % 3;
    float v = 0.f;
    if (grp == 0) {
        int dw = k >> 4, ci = k & 15;
        v = w[((((co * 16 + ci) * 3 + da) * 3 + db) * 3 + dh) * 3 + dw];
    } else if (k < 16) {
        v = w[((((co * 16 + k) * 3 + da) * 3 + db) * 3 + dh) * 3 + 2];
    }
    o[i] = f2bf(v);
}

__global__ __launch_bounds__(256) void wtrans2(const float* __restrict__ w,
                                               u16* __restrict__ o) {
    int i = blockIdx.x * 256 + threadIdx.x;
    if (i >= 82944) return;
    int ci = i & 31;
    int co = (i >> 5) & 31;
    int t  = (i >> 10) % 9;
    int p  = (i >> 10) / 9;
    int da = p / 3, db = p % 3, dh = t / 3, dw = t % 3;
    o[i] = f2bf(w[((((co * 32 + ci) * 3 + da) * 3 + db) * 3 + dh) * 3 + dw]);
}

// ---------------------------------------------------------------------------
// Image: [ci16][spatial] fp32 -> [spatial][ci16] bf16 (channel-last)
// ---------------------------------------------------------------------------
__global__ __launch_bounds__(256) void imgtrans(const float* __restrict__ img,
                                                u16* __restrict__ o) {
    int p = blockIdx.x * 256 + threadIdx.x;
    u16 r[16];
    #pragma unroll
    for (int c = 0; c < 16; ++c)
        r[c] = f2bf(img[(size_t)c * SPATIAL + p]);
    u16x8 lo, hi;
    #pragma unroll
    for (int j = 0; j < 8; ++j) { lo[j] = r[j]; hi[j] = r[8 + j]; }
    u16x8* dst = (u16x8*)(o + (size_t)p * 16);
    dst[0] = lo;
    dst[1] = hi;
}

// ---------------------------------------------------------------------------
// Conv1: Cin=16, K = dw(2)x ci(16) packing + dw2 group. Row-shared A-frags:
// wave owns wseg = wv*16, rows r=0..7; frag(x,grp) feeds all dh.
// LDS pos stride 24 u16 (48B, 16B-aligned): 2-way banks -> free.
// ---------------------------------------------------------------------------
__global__ __launch_bounds__(256, 2)
void conv1_mfma(const u16* __restrict__ xT, const u16* __restrict__ w1t,
                u16* __restrict__ y1, float* __restrict__ st1)
{
    __shared__ __align__(16) u16 lds[660 * 24];   // 31680 B
    __shared__ float sred[64];

    const int tid = threadIdx.x;
    int a, b, h0;
    decode_block(blockIdx.x, a, b, h0);
    const int lane = tid & 63;
    const int wv   = tid >> 6;
    const int kq   = lane >> 4;
    const int m    = lane & 15;
    const int wseg = wv << 4;

    unsigned pm = 0;
    #pragma unroll
    for (int p = 0; p < 9; ++p) {
        int ap = a + p / 3 - 1, bp = b + p % 3 - 1;
        if (ap >= 0 && ap < D1 && bp >= 0 && bp < D2) pm |= 1u << p;
    }

    // plane-invariant staging offsets (6 granules/thread max, 16 B each)
    const int p0 = tid >> 1, g = tid & 1;
    unsigned vmask = 0;
    int goff[6];
    #pragma unroll
    for (int k = 0; k < 6; ++k) {
        int pos = p0 + 128 * k;
        int row = pos / 66, col = pos - row * 66;
        int h = h0 - 1 + row, w = col - 1;
        bool v = (pos < 660) && col >= 1 && col <= 64 && h >= 0 && h < HH;
        goff[k] = v ? (h * WW + w) * 16 + g * 8 : 0;
        vmask |= (unsigned)v << k;
    }
    const int lbase = p0 * 24 + g * 8;

    // zero pad/OOB cells once
    for (int e = tid; e < 660; e += 256) {
        int row = e / 66, col = e - row * 66;
        int h = h0 - 1 + row;
        if (col == 0 || col == 65 || h < 0 || h >= HH) {
            u16x8 z = (u16x8)0;
            *(u16x8*)&lds[e * 24]     = z;
            *(u16x8*)&lds[e * 24 + 8] = z;
        }
    }

    f32x4 acc[8][2];
    #pragma unroll
    for (int i = 0; i < 8; ++i)
        #pragma unroll
        for (int nt = 0; nt < 2; ++nt)
            acc[i][nt] = (f32x4)0.f;

    int p = 0;
    while (!((pm >> p) & 1)) ++p;

    u16x8 pf[6];
    {
        int ap = a + p / 3 - 1, bp = b + p % 3 - 1;
        const u16* src = xT + (size_t)(ap * D2 + bp) * (HH * WW * 16);
        #pragma unroll
        for (int k = 0; k < 6; ++k)
            if ((vmask >> k) & 1) pf[k] = *(const u16x8*)(src + goff[k]);
    }

    while (p < 9) {
        int pn = p + 1;
        while (pn < 9 && !((pm >> pn) & 1)) ++pn;

        #pragma unroll
        for (int k = 0; k < 6; ++k)
            if ((vmask >> k) & 1) *(u16x8*)&lds[lbase + k * 3072] = pf[k];
        __syncthreads();

        if (pn < 9) {   // prefetch next plane during MFMA phase
            int ap = a + pn / 3 - 1, bp = b + pn % 3 - 1;
            const u16* src = xT + (size_t)(ap * D2 + bp) * (HH * WW * 16);
            #pragma unroll
            for (int k = 0; k < 6; ++k)
                if ((vmask >> k) & 1) pf[k] = *(const u16x8*)(src + goff[k]);
        }

        const u16* wbase = w1t + p * 6144;
        #pragma unroll
        for (int grp = 0; grp < 2; ++grp) {
            s16x8 bf[3][2];
            #pragma unroll
            for (int dh = 0; dh < 3; ++dh) {
                const u16* wb = wbase + (dh * 2 + grp) * 1024;
                bf[dh][0] = *(const s16x8*)(wb + m * 32 + kq * 8);
                bf[dh][1] = *(const s16x8*)(wb + (m + 16) * 32 + kq * 8);
            }
            const int cshift = (grp == 0) ? (kq >> 1) : 2;
            const int ebase  = (kq & 1) * 8;
            #pragma unroll
            for (int x = 0; x < 10; ++x) {
                int pos = x * 66 + wseg + m + cshift;
                s16x8 af = *(const s16x8*)&lds[pos * 24 + ebase];
                #pragma unroll
                for (int dh = 0; dh < 3; ++dh) {
                    int i = x - dh;
                    if (i >= 0 && i < 8) {
                        acc[i][0] = __builtin_amdgcn_mfma_f32_16x16x32_bf16(af, bf[dh][0], acc[i][0], 0, 0, 0);
                        acc[i][1] = __builtin_amdgcn_mfma_f32_16x16x32_bf16(af, bf[dh][1], acc[i][1], 0, 0, 0);
                    }
                }
            }
        }
        __syncthreads();
        p = pn;
    }

    // epilogue: channel-last bf16 store + fused per-channel stats
    if (tid < 64) sred[tid] = 0.f;
    __syncthreads();

    float s[2] = {0.f, 0.f}, s2[2] = {0.f, 0.f};
    const size_t plane_out = (size_t)(a * D2 + b) * (HH * WW);
    #pragma unroll
    for (int i = 0; i < 8; ++i) {
        int h  = h0 + i;
        int w0 = wseg + kq * 4;
        #pragma unroll
        for (int nt = 0; nt < 2; ++nt) {
            int co = m + nt * 16;
            #pragma unroll
            for (int reg = 0; reg < 4; ++reg) {
                float v = acc[i][nt][reg];
                s[nt]  += v;
                s2[nt] += v * v;
                y1[(plane_out + h * WW + (w0 + reg)) * 32 + co] = f2bf(v);
            }
        }
    }
    #pragma unroll
    for (int nt = 0; nt < 2; ++nt) {
        s[nt]  += __shfl_xor(s[nt], 16);  s[nt]  += __shfl_xor(s[nt], 32);
        s2[nt] += __shfl_xor(s2[nt], 16); s2[nt] += __shfl_xor(s2[nt], 32);
    }
    if (kq == 0) {
        atomicAdd(&sred[m * 2],            s[0]);
        atomicAdd(&sred[m * 2 + 1],        s2[0]);
        atomicAdd(&sred[(m + 16) * 2],     s[1]);
        atomicAdd(&sred[(m + 16) * 2 + 1], s2[1]);
    }
    __syncthreads();
    if (tid < 64) atomicAdd(&st1[tid], sred[tid]);
}

// ---------------------------------------------------------------------------
// norm1: in-place instance-norm + leaky on y1 (channel-last bf16).
// ---------------------------------------------------------------------------
__global__ __launch_bounds__(256)
void norm1_kernel(u16* __restrict__ y1, const float* __restrict__ st1)
{
    const int tid = threadIdx.x;
    const int q   = tid & 3;
    const float invN = 1.f / (float)SPATIAL;
    float mean[8], scl[8];
    #pragma unroll
    for (int j = 0; j < 8; ++j) {
        int ci  = q * 8 + j;
        float mu = st1[ci * 2] * invN;
        float va = st1[ci * 2 + 1] * invN - mu * mu;
        mean[j] = mu;
        scl[j]  = rsqrtf(va + EPS);
    }
    #pragma unroll
    for (int j4 = 0; j4 < 4; ++j4) {
        size_t gidx = (size_t)blockIdx.x * 1024 + j4 * 256 + tid;
        u16x8* ptr = (u16x8*)(y1 + gidx * 8);
        u16x8 v = *ptr;
        u16x8 o;
        #pragma unroll
        for (int j = 0; j < 8; ++j)
            o[j] = f2bf(leaky((bf2f(v[j]) - mean[j]) * scl[j]));
        *ptr = o;
    }
}

// ---------------------------------------------------------------------------
// Conv2: Cin=32, row-shared A-frags (wave owns wseg=wv*16, rows 0..7):
// frag(x,dw) read once, feeds dh=0..2 (6 MFMAs). Reads/plane/wave: 30 vs 72.
// LDS pos stride 40 u16 (80B): 2-way banks -> free.
// ---------------------------------------------------------------------------
__global__ __launch_bounds__(256, 2)
void conv2_mfma(const u16* __restrict__ y1, const u16* __restrict__ w2t,
                u16* __restrict__ y2, float* __restrict__ st2)
{
    __shared__ __align__(16) u16 lds[660 * 40];   // 52800 B
    __shared__ float sred[64];

    const int tid = threadIdx.x;
    int a, b, h0;
    decode_block(blockIdx.x, a, b, h0);
    const int lane = tid & 63;
    const int wv   = tid >> 6;
    const int kq   = lane >> 4;
    const int m    = lane & 15;
    const int wseg = wv << 4;

    unsigned pm = 0;
    #pragma unroll
    for (int p = 0; p < 9; ++p) {
        int ap = a + p / 3 - 1, bp = b + p % 3 - 1;
        if (ap >= 0 && ap < D1 && bp >= 0 && bp < D2) pm |= 1u << p;
    }

    // plane-invariant staging offsets (11 granules/thread max)
    const int p0 = tid >> 2, q = tid & 3;
    unsigned vmask = 0;
    int goff[11];
    #pragma unroll
    for (int k = 0; k < 11; ++k) {
        int pos = p0 + 64 * k;
        int row = pos / 66, col = pos - row * 66;
        int h = h0 - 1 + row, w = col - 1;
        bool v = (pos < 660) && col >= 1 && col <= 64 && h >= 0 && h < HH;
        goff[k] = v ? (h * WW + w) * 32 + q * 8 : 0;
        vmask |= (unsigned)v << k;
    }
    const int lbase = p0 * 40 + q * 8;

    for (int e = tid; e < 660; e += 256) {
        int row = e / 66, col = e - row * 66;
        int h = h0 - 1 + row;
        if (col == 0 || col == 65 || h < 0 || h >= HH) {
            u16x8 z = (u16x8)0;
            #pragma unroll
            for (int gg = 0; gg < 4; ++gg)
                *(u16x8*)&lds[e * 40 + gg * 8] = z;
        }
    }

    f32x4 acc[8][2];
    #pragma unroll
    for (int i = 0; i < 8; ++i)
        #pragma unroll
        for (int nt = 0; nt < 2; ++nt)
            acc[i][nt] = (f32x4)0.f;

    int p = 0;
    while (!((pm >> p) & 1)) ++p;

    u16x8 pf[11];
    {
        int ap = a + p / 3 - 1, bp = b + p % 3 - 1;
        const u16* src = y1 + (size_t)(ap * D2 + bp) * (HH * WW * 32);
        #pragma unroll
        for (int k = 0; k < 11; ++k)
            if ((vmask >> k) & 1) pf[k] = *(const u16x8*)(src + goff[k]);
    }

    while (p < 9) {
        int pn = p + 1;
        while (pn < 9 && !((pm >> pn) & 1)) ++pn;

        #pragma unroll
        for (int k = 0; k < 11; ++k)
            if ((vmask >> k) & 1) *(u16x8*)&lds[lbase + k * 2560] = pf[k];
        __syncthreads();

        if (pn < 9) {   // prefetch next plane during MFMA phase
            int ap = a + pn / 3 - 1, bp = b + pn % 3 - 1;
            const u16* src = y1 + (size_t)(ap * D2 + bp) * (HH * WW * 32);
            #pragma unroll
            for (int k = 0; k < 11; ++k)
                if ((vmask >> k) & 1) pf[k] = *(const u16x8*)(src + goff[k]);
        }

        const u16* wbase = w2t + p * 9216;
        #pragma unroll
        for (int dw = 0; dw < 3; ++dw) {
            s16x8 bf[3][2];
            #pragma unroll
            for (int dh = 0; dh < 3; ++dh) {
                const u16* wb = wbase + (dh * 3 + dw) * 1024;
                bf[dh][0] = *(const s16x8*)(wb + m * 32 + kq * 8);
                bf[dh][1] = *(const s16x8*)(wb + (m + 16) * 32 + kq * 8);
            }
            #pragma unroll
            for (int x = 0; x < 10; ++x) {
                int pos = x * 66 + wseg + dw + m;
                s16x8 af = *(const s16x8*)&lds[pos * 40 + kq * 8];
                #pragma unroll
                for (int dh = 0; dh < 3; ++dh) {
                    int i = x - dh;
                    if (i >= 0 && i < 8) {
                        acc[i][0] = __builtin_amdgcn_mfma_f32_16x16x32_bf16(af, bf[dh][0], acc[i][0], 0, 0, 0);
                        acc[i][1] = __builtin_amdgcn_mfma_f32_16x16x32_bf16(af, bf[dh][1], acc[i][1], 0, 0, 0);
                    }
                }
            }
        }
        __syncthreads();
        p = pn;
    }

    // epilogue: channel-first bf16 + fused stats
    if (tid < 64) sred[tid] = 0.f;
    __syncthreads();

    float s[2] = {0.f, 0.f}, s2[2] = {0.f, 0.f};
    #pragma unroll
    for (int i = 0; i < 8; ++i) {
        int h  = h0 + i;
        int w0 = wseg + kq * 4;
        #pragma unroll
        for (int nt = 0; nt < 2; ++nt) {
            int co = m + nt * 16;
            u16x4 pk;
            #pragma unroll
            for (int reg = 0; reg < 4; ++reg) {
                float v = acc[i][nt][reg];
                s[nt]  += v;
                s2[nt] += v * v;
                pk[reg] = f2bf(v);
            }
            size_t off = ((size_t)(co * D1 + a) * D2 + b) * (HH * WW) + h * WW + w0;
            *(u16x4*)(y2 + off) = pk;
        }
    }
    #pragma unroll
    for (int nt = 0; nt < 2; ++nt) {
        s[nt]  += __shfl_xor(s[nt], 16);  s[nt]  += __shfl_xor(s[nt], 32);
        s2[nt] += __shfl_xor(s2[nt], 16); s2[nt] += __shfl_xor(s2[nt], 32);
    }
    if (kq == 0) {
        atomicAdd(&sred[m * 2],            s[0]);
        atomicAdd(&sred[m * 2 + 1],        s2[0]);
        atomicAdd(&sred[(m + 16) * 2],     s[1]);
        atomicAdd(&sred[(m + 16) * 2 + 1], s2[1]);
    }
    __syncthreads();
    if (tid < 64) atomicAdd(&st2[tid], sred[tid]);
}

// ---------------------------------------------------------------------------
// Final: norm + leaky, bf16 channel-first -> fp32 channel-first d_out
// ---------------------------------------------------------------------------
__global__ __launch_bounds__(256)
void norm2_kernel(const u16* __restrict__ y2, const float* __restrict__ st2,
                  float* __restrict__ out)
{
    size_t i4 = (size_t)blockIdx.x * 256 + threadIdx.x;
    int c = (int)(i4 >> 17);
    const float invN = 1.f / (float)SPATIAL;
    float mu = st2[c * 2] * invN;
    float va = st2[c * 2 + 1] * invN - mu * mu;
    float sc = rsqrtf(va + EPS);
    u16x4 v = *(const u16x4*)(y2 + i4 * 4);
    float4 o;
    o.x = leaky((bf2f(v[0]) - mu) * sc);
    o.y = leaky((bf2f(v[1]) - mu) * sc);
    o.z = leaky((bf2f(v[2]) - mu) * sc);
    o.w = leaky((bf2f(v[3]) - mu) * sc);
    *(float4*)(out + i4 * 4) = o;
}

// ---------------------------------------------------------------------------
extern "C" void kernel_launch(void* const* d_in, const int* in_sizes, int n_in,
                              void* d_out, int out_size, void* d_ws, size_t ws_size,
                              hipStream_t stream)
{
    const float* image = (const float*)d_in[0];
    const float* w1    = (const float*)d_in[1];
    const float* w2    = (const float*)d_in[2];
    float* out = (float*)d_out;

    // ws: [0,32MB) imgT (reused as y2) | [32MB,64MB) y1 | [64MB,+512B) stats
    u16*   imgT = (u16*)d_ws;
    u16*   y1   = (u16*)((char*)d_ws + 33554432);
    u16*   y2   = imgT;
    float* st   = (float*)((char*)d_ws + 67108864);
    float* st1  = st;
    float* st2  = st + 64;

    // weight tables live in d_out's tail; dead before norm2 overwrites d_out
    u16* w1t = (u16*)((char*)d_out + 66832384);   // 55296 bf16
    u16* w2t = (u16*)((char*)d_out + 66942976);   // 82944 bf16

    hipMemsetAsync(st, 0, 512, stream);
    wtrans1<<<216, 256, 0, stream>>>(w1, w1t);
    wtrans2<<<324, 256, 0, stream>>>(w2, w2t);
    imgtrans<<<2048, 256, 0, stream>>>(image, imgT);

    conv1_mfma<<<1024, 256, 0, stream>>>(imgT, w1t, y1, st1);
    norm1_kernel<<<2048, 256, 0, stream>>>(y1, st1);
    conv2_mfma<<<1024, 256, 0, stream>>>(y1, w2t, y2, st2);
    norm2_kernel<<<16384, 256, 0, stream>>>(y2, st2, out);
}